// Round 4
// baseline (408.796 us; speedup 1.0000x reference)
//
#include <hip/hip_runtime.h>
#include <hip/hip_bf16.h>

#define M_   16384   // B*N tokens
#define K_   1024    // E
#define NQKV 3072    // 3*E output cols

typedef _Float16 f16x8 __attribute__((ext_vector_type(8)));
typedef float    f32x4 __attribute__((ext_vector_type(4)));

// C[m,n] = sum_k x[m,k] * W[n,k] + bias[n]; three weight segments (q,k,v).
// fp32 inputs, converted to fp16 during LDS staging (2^-11 rounding, 4x tighter
// than bf16 -- needed for the softmax-amplified error budget). fp16 out -> ws.
// Tile 128x128, BK=64, 256 threads (4 waves, 2x2 wave grid, 4x4 16x16 MFMA tiles/wave).
__global__ __launch_bounds__(256) void gemm_qkv(
    const float* __restrict__ x,
    const float* __restrict__ Wq, const float* __restrict__ bq,
    const float* __restrict__ Wk, const float* __restrict__ bk,
    const float* __restrict__ Wv, const float* __restrict__ bv,
    _Float16* __restrict__ qkv)
{
  __shared__ __align__(16) _Float16 As[128 * 64];
  __shared__ __align__(16) _Float16 Bs[128 * 64];

  const int tid  = threadIdx.x;
  const int ln   = tid & 63;
  const int w    = tid >> 6;
  const int wm   = w >> 1, wn = w & 1;
  const int lcol = ln & 15, quad = ln >> 4;

  const int m0  = blockIdx.y * 128;
  const int n0  = blockIdx.x * 128;          // 0..3071, 128-aligned -> one segment
  const int seg = n0 >> 10;
  const int n0s = n0 & 1023;

  const float* Wp = (seg == 0) ? Wq : ((seg == 1) ? Wk : Wv);
  const float* bp = (seg == 0) ? bq : ((seg == 1) ? bk : bv);
  _Float16* Cp = qkv + (size_t)seg * ((size_t)M_ * 1024);

  f32x4 acc[4][4];
#pragma unroll
  for (int i = 0; i < 4; i++)
#pragma unroll
    for (int j = 0; j < 4; j++) acc[i][j] = f32x4{0.f, 0.f, 0.f, 0.f};

  for (int k0 = 0; k0 < K_; k0 += 64) {
    // Stage + convert: 1024 f16x8 chunks per tile; 256 threads x 4 chunks each.
#pragma unroll
    for (int i = 0; i < 4; ++i) {
      const int e   = i * 256 + tid;          // chunk 0..1023
      const int row = e >> 3, c = (e & 7) * 8;
      const float* ax = x  + (size_t)(m0  + row) * K_ + k0 + c;
      const float* bx = Wp + (size_t)(n0s + row) * K_ + k0 + c;
      float4 a0 = *(const float4*)ax;
      float4 a1 = *(const float4*)(ax + 4);
      float4 b0 = *(const float4*)bx;
      float4 b1 = *(const float4*)(bx + 4);
      f16x8 av, bv8;
      av[0] = (_Float16)a0.x; av[1] = (_Float16)a0.y; av[2] = (_Float16)a0.z; av[3] = (_Float16)a0.w;
      av[4] = (_Float16)a1.x; av[5] = (_Float16)a1.y; av[6] = (_Float16)a1.z; av[7] = (_Float16)a1.w;
      bv8[0] = (_Float16)b0.x; bv8[1] = (_Float16)b0.y; bv8[2] = (_Float16)b0.z; bv8[3] = (_Float16)b0.w;
      bv8[4] = (_Float16)b1.x; bv8[5] = (_Float16)b1.y; bv8[6] = (_Float16)b1.z; bv8[7] = (_Float16)b1.w;
      *(f16x8*)&As[e * 8] = av;
      *(f16x8*)&Bs[e * 8] = bv8;
    }
    __syncthreads();

#pragma unroll
    for (int kk = 0; kk < 64; kk += 32) {
      f16x8 a[4], b[4];
#pragma unroll
      for (int mi = 0; mi < 4; mi++)
        a[mi] = *(const f16x8*)&As[(wm * 64 + mi * 16 + lcol) * 64 + kk + quad * 8];
#pragma unroll
      for (int ni = 0; ni < 4; ni++)
        b[ni] = *(const f16x8*)&Bs[(wn * 64 + ni * 16 + lcol) * 64 + kk + quad * 8];
#pragma unroll
      for (int mi = 0; mi < 4; mi++)
#pragma unroll
        for (int ni = 0; ni < 4; ni++)
          acc[mi][ni] = __builtin_amdgcn_mfma_f32_16x16x32_f16(a[mi], b[ni], acc[mi][ni], 0, 0, 0);
    }
    __syncthreads();
  }

  // Epilogue: C/D layout col=lane&15, row=quad*4+reg. Add fp32 bias, store fp16.
#pragma unroll
  for (int ni = 0; ni < 4; ni++) {
    const int col  = n0s + wn * 64 + ni * 16 + lcol;
    const float bi = bp[col];
#pragma unroll
    for (int mi = 0; mi < 4; mi++) {
      const int r0 = m0 + wm * 64 + mi * 16 + quad * 4;
#pragma unroll
      for (int r = 0; r < 4; r++)
        Cp[(size_t)(r0 + r) * 1024 + col] = (_Float16)(acc[mi][ni][r] + bi);
    }
  }
}

// One wave per token. QKV fp16 in ws; fp32 pattern; fp32 output.
__global__ __launch_bounds__(256) void attn_kernel(
    const _Float16* __restrict__ qkv,
    const float* __restrict__ pat,
    float* __restrict__ out)
{
  // per wave: q[16*68] k[16*68] v[16*68] attn[256]  (pad 68 -> conflict-free)
  __shared__ float sh[4][3 * 1088 + 256];
  const int ln = threadIdx.x & 63;
  const int wv = threadIdx.x >> 6;
  const int t  = blockIdx.x * 4 + wv;

  float* shq = sh[wv];
  float* shk = shq + 1088;
  float* shv = shk + 1088;
  float* sha = shv + 1088;

  const _Float16* qg = qkv + (size_t)t * 1024;
  const _Float16* kg = qg + (size_t)M_ * 1024;
  const _Float16* vg = kg + (size_t)M_ * 1024;

#pragma unroll
  for (int i = 0; i < 2; i++) {
    const int e = i * 64 + ln;            // 16B chunk index 0..127
    const int r = e >> 3, c = (e & 7) * 8;
    f16x8 qc = *(const f16x8*)(qg + e * 8);
    f16x8 kc = *(const f16x8*)(kg + e * 8);
    f16x8 vc = *(const f16x8*)(vg + e * 8);
#pragma unroll
    for (int j = 0; j < 8; j++) {
      shq[r * 68 + c + j] = (float)qc[j];
      shk[r * 68 + c + j] = (float)kc[j];
      shv[r * 68 + c + j] = (float)vc[j];
    }
  }
  __syncthreads();

  // scores: lane handles (h = i*4 + (ln>>4), g = ln&15), i = 0..3
  const int g = ln & 15, hq = ln >> 4;
#pragma unroll
  for (int i = 0; i < 4; i++) {
    const int h = i * 4 + hq;
    float s = 0.f;
#pragma unroll
    for (int d = 0; d < 64; d++) s += shq[h * 68 + d] * shk[g * 68 + d];
    s *= pat[h * 16 + g];                 // multiplicative mask BEFORE softmax
    float m = s;
#pragma unroll
    for (int msk = 1; msk < 16; msk <<= 1) m = fmaxf(m, __shfl_xor(m, msk, 64));
    const float e = __expf(s - m);
    float sum = e;
#pragma unroll
    for (int msk = 1; msk < 16; msk <<= 1) sum += __shfl_xor(sum, msk, 64);
    sha[h * 16 + g] = e / sum;
  }
  __syncthreads();

  // PV: lane = d column; out[h][d] = sum_g attn[h][g] * v[g][d]
  float o[16];
#pragma unroll
  for (int h = 0; h < 16; h++) o[h] = 0.f;
#pragma unroll
  for (int gg = 0; gg < 16; gg++) {
    const float vv = shv[gg * 68 + ln];
#pragma unroll
    for (int h = 0; h < 16; h++) o[h] += sha[h * 16 + gg] * vv;
  }
  float* op = out + (size_t)t * 1024 + ln;
#pragma unroll
  for (int h = 0; h < 16; h++) op[h * 64] = o[h];
}

extern "C" void kernel_launch(void* const* d_in, const int* in_sizes, int n_in,
                              void* d_out, int out_size, void* d_ws, size_t ws_size,
                              hipStream_t stream) {
  const float* x   = (const float*)d_in[0];
  const float* pat = (const float*)d_in[1];
  const float* Wq  = (const float*)d_in[2];
  const float* bq  = (const float*)d_in[3];
  const float* Wk  = (const float*)d_in[4];
  const float* bk  = (const float*)d_in[5];
  const float* Wv  = (const float*)d_in[6];
  const float* bv  = (const float*)d_in[7];

  _Float16* qkvh = (_Float16*)d_ws;  // [3][16384][1024] fp16 = 96 MiB

  dim3 g1(NQKV / 128, M_ / 128);
  gemm_qkv<<<g1, 256, 0, stream>>>(x, Wq, bq, Wk, bk, Wv, bv, qkvh);
  attn_kernel<<<M_ / 4, 256, 0, stream>>>(qkvh, pat, (float*)d_out);
}

// Round 5
// 394.224 us; speedup vs baseline: 1.0370x; 1.0370x over previous
//
#include <hip/hip_runtime.h>
#include <hip/hip_bf16.h>

#define M_   16384   // B*N tokens
#define K_   1024    // E
#define NQKV 3072    // 3*E output cols

typedef _Float16 f16x8 __attribute__((ext_vector_type(8)));
typedef float    f32x4 __attribute__((ext_vector_type(4)));

// C[m,n] = sum_k x[m,k] * W[n,k] + bias[n]; three weight segments (q,k,v).
// fp32 in -> fp16 LDS tiles (cvt in staging), fp16 out -> ws.
// 128x128 tile, BK=64, 4 waves. XOR-swizzled LDS chunks (kill 16-way bank
// conflicts) + register prefetch of next tile across the MFMA section.
// grid(128 m-tiles, 24 n-tiles): same-m blocks spread, m-stripes pin to XCDs.
__global__ __launch_bounds__(256, 3) void gemm_qkv(
    const float* __restrict__ x,
    const float* __restrict__ Wq, const float* __restrict__ bq,
    const float* __restrict__ Wk, const float* __restrict__ bk,
    const float* __restrict__ Wv, const float* __restrict__ bv,
    _Float16* __restrict__ qkv)
{
  __shared__ __align__(16) _Float16 As[128 * 64];
  __shared__ __align__(16) _Float16 Bs[128 * 64];

  const int tid  = threadIdx.x;
  const int ln   = tid & 63;
  const int w    = tid >> 6;
  const int wm   = w >> 1, wn = w & 1;
  const int lcol = ln & 15, quad = ln >> 4;
  const int sw   = lcol & 7;              // row&7 for all fragment rows

  const int m0  = blockIdx.x * 128;
  const int n0  = blockIdx.y * 128;
  const int seg = n0 >> 10;
  const int n0s = n0 & 1023;

  const float* Wp = (seg == 0) ? Wq : ((seg == 1) ? Wk : Wv);
  const float* bp = (seg == 0) ? bq : ((seg == 1) ? bk : bv);
  _Float16* Cp = qkv + (size_t)seg * ((size_t)M_ * 1024);

  // Per-thread staging coords: chunk e = i*256+tid -> row=e>>3, cc=e&7.
  int offs_[4];
  const float* gA[4];
  const float* gB[4];
#pragma unroll
  for (int i = 0; i < 4; i++) {
    const int e = i * 256 + tid, row = e >> 3, cc = e & 7;
    offs_[i] = row * 64 + ((cc ^ (row & 7)) * 8);   // swizzled LDS offset
    gA[i] = x  + (size_t)(m0  + row) * K_ + cc * 8;
    gB[i] = Wp + (size_t)(n0s + row) * K_ + cc * 8;
  }

  f32x4 acc[4][4];
#pragma unroll
  for (int i = 0; i < 4; i++)
#pragma unroll
    for (int j = 0; j < 4; j++) acc[i][j] = f32x4{0.f, 0.f, 0.f, 0.f};

  float4 RA[4][2], RB[4][2];
#pragma unroll
  for (int i = 0; i < 4; i++) {
    RA[i][0] = *(const float4*)(gA[i]);
    RA[i][1] = *(const float4*)(gA[i] + 4);
    RB[i][0] = *(const float4*)(gB[i]);
    RB[i][1] = *(const float4*)(gB[i] + 4);
  }

  for (int k0 = 0; k0 < K_; k0 += 64) {
    __syncthreads();                      // previous tile's readers done
#pragma unroll
    for (int i = 0; i < 4; i++) {
      f16x8 av, bv8;
      av[0]=(_Float16)RA[i][0].x; av[1]=(_Float16)RA[i][0].y;
      av[2]=(_Float16)RA[i][0].z; av[3]=(_Float16)RA[i][0].w;
      av[4]=(_Float16)RA[i][1].x; av[5]=(_Float16)RA[i][1].y;
      av[6]=(_Float16)RA[i][1].z; av[7]=(_Float16)RA[i][1].w;
      bv8[0]=(_Float16)RB[i][0].x; bv8[1]=(_Float16)RB[i][0].y;
      bv8[2]=(_Float16)RB[i][0].z; bv8[3]=(_Float16)RB[i][0].w;
      bv8[4]=(_Float16)RB[i][1].x; bv8[5]=(_Float16)RB[i][1].y;
      bv8[6]=(_Float16)RB[i][1].z; bv8[7]=(_Float16)RB[i][1].w;
      *(f16x8*)&As[offs_[i]] = av;
      *(f16x8*)&Bs[offs_[i]] = bv8;
    }
    if (k0 + 64 < K_) {                   // prefetch next tile; in flight over MFMA
      const int kn = k0 + 64;
#pragma unroll
      for (int i = 0; i < 4; i++) {
        RA[i][0] = *(const float4*)(gA[i] + kn);
        RA[i][1] = *(const float4*)(gA[i] + kn + 4);
        RB[i][0] = *(const float4*)(gB[i] + kn);
        RB[i][1] = *(const float4*)(gB[i] + kn + 4);
      }
    }
    __syncthreads();

#pragma unroll
    for (int kk = 0; kk < 64; kk += 32) {
      const int kc = kk >> 3;             // logical chunk base: 0 or 4
      f16x8 a[4], b[4];
#pragma unroll
      for (int mi = 0; mi < 4; mi++)
        a[mi] = *(const f16x8*)&As[(wm * 64 + mi * 16 + lcol) * 64 + (((kc + quad) ^ sw) * 8)];
#pragma unroll
      for (int ni = 0; ni < 4; ni++)
        b[ni] = *(const f16x8*)&Bs[(wn * 64 + ni * 16 + lcol) * 64 + (((kc + quad) ^ sw) * 8)];
#pragma unroll
      for (int mi = 0; mi < 4; mi++)
#pragma unroll
        for (int ni = 0; ni < 4; ni++)
          acc[mi][ni] = __builtin_amdgcn_mfma_f32_16x16x32_f16(a[mi], b[ni], acc[mi][ni], 0, 0, 0);
    }
  }

  // Epilogue: C/D layout col=lane&15, row=quad*4+reg. Add fp32 bias, store fp16.
#pragma unroll
  for (int ni = 0; ni < 4; ni++) {
    const int col  = n0s + wn * 64 + ni * 16 + lcol;
    const float bi = bp[col];
#pragma unroll
    for (int mi = 0; mi < 4; mi++) {
      const int r0 = m0 + wm * 64 + mi * 16 + quad * 4;
#pragma unroll
      for (int r = 0; r < 4; r++)
        Cp[(size_t)(r0 + r) * 1024 + col] = (_Float16)(acc[mi][ni][r] + bi);
    }
  }
}

// One wave per token, MFMA micro-attention.
// QK^T: 2x mfma_16x16x32_f16 from direct global f16x8 loads.
// Masked shuffle-softmax over 16-lane groups.
// P -> fp16 via wave-private LDS transpose; PV: 4x mfma (k>=16 zero-padded).
__global__ __launch_bounds__(256) void attn_kernel(
    const _Float16* __restrict__ qkv,
    const float* __restrict__ pat,
    float* __restrict__ out)
{
  __shared__ float pat_s[256];
  __shared__ __align__(16) _Float16 Ps[4][16 * 24];  // row stride 24 f16 (48 B)

  const int tid  = threadIdx.x;
  const int ln   = tid & 63;
  const int wv   = tid >> 6;
  const int lcol = ln & 15, quad = ln >> 4;
  const int t    = blockIdx.x * 4 + wv;

  pat_s[tid] = pat[tid];
  __syncthreads();

  const _Float16* qg = qkv + (size_t)t * 1024;
  const _Float16* kg = qg + (size_t)M_ * 1024;
  const _Float16* vg = kg + (size_t)M_ * 1024;

  // QK^T: A[m=h=lcol][k=quad*8+j], B[k=quad*8+j][n=g=lcol] (row-major K rows)
  f16x8 aq0 = *(const f16x8*)(qg + lcol * 64 + quad * 8);
  f16x8 aq1 = *(const f16x8*)(qg + lcol * 64 + 32 + quad * 8);
  f16x8 bk0 = *(const f16x8*)(kg + lcol * 64 + quad * 8);
  f16x8 bk1 = *(const f16x8*)(kg + lcol * 64 + 32 + quad * 8);
  f32x4 s = {0.f, 0.f, 0.f, 0.f};
  s = __builtin_amdgcn_mfma_f32_16x16x32_f16(aq0, bk0, s, 0, 0, 0);
  s = __builtin_amdgcn_mfma_f32_16x16x32_f16(aq1, bk1, s, 0, 0, 0);

  // lane holds scores[h=quad*4+r][g=lcol]; mask then softmax over g (16 lanes)
#pragma unroll
  for (int r = 0; r < 4; r++) {
    const float sv = s[r] * pat_s[(quad * 4 + r) * 16 + lcol];
    float m = sv;
#pragma unroll
    for (int msk = 1; msk < 16; msk <<= 1) m = fmaxf(m, __shfl_xor(m, msk, 64));
    const float e = __expf(sv - m);
    float su = e;
#pragma unroll
    for (int msk = 1; msk < 16; msk <<= 1) su += __shfl_xor(su, msk, 64);
    // write P[h][g] fp16 for the PV A-fragment transpose
    Ps[wv][(quad * 4 + r) * 24 + lcol] = (_Float16)(e / su);
  }

  // A-frag for PV: lane m=lcol, k=quad*8+j; valid k<16 -> quads 0,1 only
  f16x8 ap = {};
  if (quad < 2) ap = *(const f16x8*)&Ps[wv][lcol * 24 + quad * 8];

  // PV per 16-wide d-tile: B[k=g=quad*8+j][n=lcol] = V[g][dt*16+lcol]
  f32x4 o[4];
#pragma unroll
  for (int dt = 0; dt < 4; dt++) {
    f16x8 bvf = {};
    if (quad < 2) {
#pragma unroll
      for (int j = 0; j < 8; j++)
        bvf[j] = vg[(quad * 8 + j) * 64 + dt * 16 + lcol];
    }
    f32x4 z = {0.f, 0.f, 0.f, 0.f};
    o[dt] = __builtin_amdgcn_mfma_f32_16x16x32_f16(ap, bvf, z, 0, 0, 0);
  }

  // C layout: row h=quad*4+r, col d=dt*16+lcol
  float* op = out + (size_t)t * 1024;
#pragma unroll
  for (int dt = 0; dt < 4; dt++)
#pragma unroll
    for (int r = 0; r < 4; r++)
      op[(quad * 4 + r) * 64 + dt * 16 + lcol] = o[dt][r];
}

extern "C" void kernel_launch(void* const* d_in, const int* in_sizes, int n_in,
                              void* d_out, int out_size, void* d_ws, size_t ws_size,
                              hipStream_t stream) {
  const float* x   = (const float*)d_in[0];
  const float* pat = (const float*)d_in[1];
  const float* Wq  = (const float*)d_in[2];
  const float* bq  = (const float*)d_in[3];
  const float* Wk  = (const float*)d_in[4];
  const float* bk  = (const float*)d_in[5];
  const float* Wv  = (const float*)d_in[6];
  const float* bv  = (const float*)d_in[7];

  _Float16* qkvh = (_Float16*)d_ws;  // [3][16384][1024] fp16 = 96 MiB

  dim3 g1(M_ / 128, NQKV / 128);
  gemm_qkv<<<g1, 256, 0, stream>>>(x, Wq, bq, Wk, bk, Wv, bv, qkvh);
  attn_kernel<<<M_ / 4, 256, 0, stream>>>(qkvh, pat, (float*)d_out);
}

// Round 6
// 312.564 us; speedup vs baseline: 1.3079x; 1.2613x over previous
//
#include <hip/hip_runtime.h>
#include <hip/hip_bf16.h>

#define M_   16384   // B*N tokens
#define K_   1024    // E
#define NQKV 3072    // 3*E output cols

typedef _Float16 f16x4 __attribute__((ext_vector_type(4)));
typedef _Float16 f16x8 __attribute__((ext_vector_type(8)));
typedef float    f32x4 __attribute__((ext_vector_type(4)));

// fp32 -> fp16 grid-stride convert (float4 granularity)
__global__ __launch_bounds__(256) void cvt_f32_f16(const float* __restrict__ in,
                                                   _Float16* __restrict__ o, int n4) {
  int i = blockIdx.x * blockDim.x + threadIdx.x;
  const int stride = gridDim.x * blockDim.x;
  for (; i < n4; i += stride) {
    float4 v = ((const float4*)in)[i];
    f16x4 h; h[0] = (_Float16)v.x; h[1] = (_Float16)v.y;
    h[2] = (_Float16)v.z; h[3] = (_Float16)v.w;
    *(f16x4*)&o[(size_t)i * 4] = h;
  }
}

// m97-structure GEMM: fp16 in (pre-converted), global_load_lds width-16 staging,
// 128x128 tile, BK=64, 4 waves, 16x16x32 MFMA. qkv out: [token][3][1024] fp16.
__global__ __launch_bounds__(256) void gemm_qkv(
    const _Float16* __restrict__ xh, const _Float16* __restrict__ wh,
    const float* __restrict__ bq, const float* __restrict__ bk,
    const float* __restrict__ bv, _Float16* __restrict__ qkv)
{
  __shared__ __align__(16) _Float16 As[128 * 64];
  __shared__ __align__(16) _Float16 Bs[128 * 64];

  const int tid  = threadIdx.x;
  const int ln   = tid & 63;
  const int w    = tid >> 6;
  const int wm   = w >> 1, wn = w & 1;
  const int lcol = ln & 15, quad = ln >> 4;

  const int m0 = blockIdx.y * 128;    // y: m-tile (slow) -> consecutive blocks share m
  const int n0 = blockIdx.x * 128;    // x: n-tile (fast), global col 0..3071

  f32x4 acc[4][4];
#pragma unroll
  for (int i = 0; i < 4; i++)
#pragma unroll
    for (int j = 0; j < 4; j++) acc[i][j] = f32x4{0.f, 0.f, 0.f, 0.f};

  for (int k0 = 0; k0 < K_; k0 += 64) {
    // Stage A,B: 1024 x 16B chunks each; LDS dest = uniform base + lane*16.
#pragma unroll
    for (int i = 0; i < 4; ++i) {
      const int cb  = w * 256 + i * 64;     // wave-uniform chunk base
      const int c   = cb + ln;
      const int row = c >> 3, cc = c & 7;
      __builtin_amdgcn_global_load_lds(
          (const __attribute__((address_space(1))) void*)(xh + (size_t)(m0 + row) * K_ + k0 + cc * 8),
          (__attribute__((address_space(3))) void*)(As + (size_t)cb * 8), 16, 0, 0);
      __builtin_amdgcn_global_load_lds(
          (const __attribute__((address_space(1))) void*)(wh + (size_t)(n0 + row) * K_ + k0 + cc * 8),
          (__attribute__((address_space(3))) void*)(Bs + (size_t)cb * 8), 16, 0, 0);
    }
    __syncthreads();

#pragma unroll
    for (int kk = 0; kk < 64; kk += 32) {
      f16x8 a[4], b[4];
#pragma unroll
      for (int mi = 0; mi < 4; mi++)
        a[mi] = *(const f16x8*)&As[(wm * 64 + mi * 16 + lcol) * 64 + kk + quad * 8];
#pragma unroll
      for (int ni = 0; ni < 4; ni++)
        b[ni] = *(const f16x8*)&Bs[(wn * 64 + ni * 16 + lcol) * 64 + kk + quad * 8];
#pragma unroll
      for (int mi = 0; mi < 4; mi++)
#pragma unroll
        for (int ni = 0; ni < 4; ni++)
          acc[mi][ni] = __builtin_amdgcn_mfma_f32_16x16x32_f16(a[mi], b[ni], acc[mi][ni], 0, 0, 0);
    }
    __syncthreads();
  }

  // Epilogue: C/D col=lane&15, row=quad*4+reg. qkv[token*3072 + col].
#pragma unroll
  for (int ni = 0; ni < 4; ni++) {
    const int col = n0 + wn * 64 + ni * 16 + lcol;
    const int seg = col >> 10, cs = col & 1023;
    const float bi = ((seg == 0) ? bq : (seg == 1) ? bk : bv)[cs];
#pragma unroll
    for (int mi = 0; mi < 4; mi++) {
      const int r0 = m0 + wm * 64 + mi * 16 + quad * 4;
#pragma unroll
      for (int r = 0; r < 4; r++)
        qkv[(size_t)(r0 + r) * 3072 + col] = (_Float16)(acc[mi][ni][r] + bi);
    }
  }
}

// One wave per token. qkv [token][3][1024] fp16. MFMA micro-attention with
// V staged transposed through wave-private LDS (no scalar global loads).
__global__ __launch_bounds__(256) void attn_kernel(
    const _Float16* __restrict__ qkv,
    const float* __restrict__ pat,
    float* __restrict__ out)
{
  __shared__ float pat_s[256];
  __shared__ __align__(16) _Float16 Ps[4][16 * 24];  // P[h][g], stride 24
  __shared__ __align__(16) _Float16 Vt[4][64 * 24];  // V^T[d][g], stride 24

  const int tid  = threadIdx.x;
  const int ln   = tid & 63;
  const int wv   = tid >> 6;
  const int lcol = ln & 15, quad = ln >> 4;
  const int t    = blockIdx.x * 4 + wv;

  pat_s[tid] = pat[tid];
  __syncthreads();

  const _Float16* qg = qkv + (size_t)t * 3072;
  const _Float16* kg = qg + 1024;
  const _Float16* vg = qg + 2048;

  // Stage V transposed: coalesced f16x8 reads, scatter to Vt[d][g].
#pragma unroll
  for (int i = 0; i < 2; i++) {
    const int e = i * 64 + ln;           // chunk 0..127 over V[16][64]
    const int g = e >> 3, c = (e & 7) * 8;
    f16x8 vc = *(const f16x8*)(vg + g * 64 + c);
#pragma unroll
    for (int j = 0; j < 8; j++) Vt[wv][(c + j) * 24 + g] = vc[j];
  }

  // QK^T: A[m=h=lcol][k=quad*8+j], B[n=g=lcol][k=quad*8+j]
  f16x8 aq0 = *(const f16x8*)(qg + lcol * 64 + quad * 8);
  f16x8 aq1 = *(const f16x8*)(qg + lcol * 64 + 32 + quad * 8);
  f16x8 bk0 = *(const f16x8*)(kg + lcol * 64 + quad * 8);
  f16x8 bk1 = *(const f16x8*)(kg + lcol * 64 + 32 + quad * 8);
  f32x4 s = {0.f, 0.f, 0.f, 0.f};
  s = __builtin_amdgcn_mfma_f32_16x16x32_f16(aq0, bk0, s, 0, 0, 0);
  s = __builtin_amdgcn_mfma_f32_16x16x32_f16(aq1, bk1, s, 0, 0, 0);

  // lane holds scores[h=quad*4+r][g=lcol]; mask, softmax over g (16 lanes)
#pragma unroll
  for (int r = 0; r < 4; r++) {
    const float sv = s[r] * pat_s[(quad * 4 + r) * 16 + lcol];
    float m = sv;
#pragma unroll
    for (int msk = 1; msk < 16; msk <<= 1) m = fmaxf(m, __shfl_xor(m, msk, 64));
    const float e = __expf(sv - m);
    float su = e;
#pragma unroll
    for (int msk = 1; msk < 16; msk <<= 1) su += __shfl_xor(su, msk, 64);
    Ps[wv][(quad * 4 + r) * 24 + lcol] = (_Float16)(e / su);
  }

  // PV: A[m=h=lcol][k=g=quad*8+j] from Ps; B[n=d][k=g] from Vt. k>=16 zero.
  f16x8 ap = {};
  if (quad < 2) ap = *(const f16x8*)&Ps[wv][lcol * 24 + quad * 8];

  f32x4 o[4];
#pragma unroll
  for (int dt = 0; dt < 4; dt++) {
    f16x8 bvf = {};
    if (quad < 2) bvf = *(const f16x8*)&Vt[wv][(dt * 16 + lcol) * 24 + quad * 8];
    f32x4 z = {0.f, 0.f, 0.f, 0.f};
    o[dt] = __builtin_amdgcn_mfma_f32_16x16x32_f16(ap, bvf, z, 0, 0, 0);
  }

  // C layout: row h=quad*4+r, col d=dt*16+lcol
  float* op = out + (size_t)t * 1024;
#pragma unroll
  for (int dt = 0; dt < 4; dt++)
#pragma unroll
    for (int r = 0; r < 4; r++)
      op[(quad * 4 + r) * 64 + dt * 16 + lcol] = o[dt][r];
}

extern "C" void kernel_launch(void* const* d_in, const int* in_sizes, int n_in,
                              void* d_out, int out_size, void* d_ws, size_t ws_size,
                              hipStream_t stream) {
  const float* x   = (const float*)d_in[0];
  const float* pat = (const float*)d_in[1];
  const float* Wq  = (const float*)d_in[2];
  const float* bq  = (const float*)d_in[3];
  const float* Wk  = (const float*)d_in[4];
  const float* bk  = (const float*)d_in[5];
  const float* Wv  = (const float*)d_in[6];
  const float* bv  = (const float*)d_in[7];

  // ws layout (f16 elements):
  //   qkvh [16384][3][1024]  @ 0           (96 MiB)
  //   xh   [16384][1024]     @ 50331648    (32 MiB)
  //   wh   [3][1024][1024]   @ 67108864    ( 6 MiB)   total ~134 MiB
  _Float16* qkvh = (_Float16*)d_ws;
  _Float16* xh   = qkvh + (size_t)50331648;
  _Float16* wh   = qkvh + (size_t)67108864;

  cvt_f32_f16<<<4096, 256, 0, stream>>>(x,  xh,               4194304);
  cvt_f32_f16<<<1024, 256, 0, stream>>>(Wq, wh,                262144);
  cvt_f32_f16<<<1024, 256, 0, stream>>>(Wk, wh + 1048576,      262144);
  cvt_f32_f16<<<1024, 256, 0, stream>>>(Wv, wh + 2097152,      262144);

  dim3 g1(NQKV / 128, M_ / 128);
  gemm_qkv<<<g1, 256, 0, stream>>>(xh, wh, bq, bk, bv, qkvh);
  attn_kernel<<<M_ / 4, 256, 0, stream>>>(qkvh, pat, (float*)d_out);
}